// Round 4
// baseline (168.203 us; speedup 1.0000x reference)
//
#include <hip/hip_runtime.h>
#include <hip/hip_bf16.h>

#define B_ 1024
#define S_ 100
#define IN_ 100
#define H_ 128
#define MID_ 32
#define OUT_ 2
#define P_ (B_ * S_)
#define RSQRT_H 0.08838834764831845f
#define LSTR 136     // klds/hlds row stride (bf16): 272 B, 16B-aligned, conflicts <=2-way
#define TILE 25      // center rows per block (4 tiles per sequence)
#define KR 32        // klds rows
#define HR 36        // hlds rows (S2 reads A rows 2..33; rows 32..35 zeroed)
#define HTS 40       // hT row stride (bf16): 80 B -> 16B-aligned, bank +20/row (2-way max)
#define SSTR 36      // score row stride (fp32)
#define WSTR 40      // band-weight row stride (bf16): 80 B

typedef __attribute__((ext_vector_type(8))) short short8;
typedef __attribute__((ext_vector_type(4))) float float4v;

__device__ __forceinline__ float bf2f(ushort u) {
    union { unsigned u; float f; } c; c.u = ((unsigned)u) << 16; return c.f;
}
__device__ __forceinline__ ushort f2bf(float x) {
    union { float f; unsigned u; } c; c.f = x;
    unsigned r = c.u + 0x7FFFu + ((c.u >> 16) & 1u);  // RNE
    return (ushort)(r >> 16);
}

// ---------------------------------------------------------------------------
// Prep (160 blocks):
//  0..143 : W1T[n][k]=W1[k][n] (k>=100 -> 0), WvT, W2T   (bf16 [n][128])
//  144..159: WqkT[n][k] = RSQRT_H * sum_j Wq[k][j]*Wk[n][j]   (scale folded!)
// ---------------------------------------------------------------------------
__global__ __launch_bounds__(256) void prep_kernel(const float* __restrict__ W1,
                                                   const float* __restrict__ Wv,
                                                   const float* __restrict__ W2,
                                                   const float* __restrict__ Wq,
                                                   const float* __restrict__ Wk,
                                                   ushort* __restrict__ W1T,
                                                   ushort* __restrict__ WvT,
                                                   ushort* __restrict__ W2T,
                                                   ushort* __restrict__ WqkT) {
    int tid = threadIdx.x;
    if (blockIdx.x < 144) {
        int g = blockIdx.x * 256 + tid;
        if (g < 16384) {
            int n = g >> 7, k = g & 127;
            W1T[g] = (k < IN_) ? f2bf(W1[k * H_ + n]) : (ushort)0;
        } else if (g < 32768) {
            int e = g - 16384; int n = e >> 7, k = e & 127;
            WvT[e] = f2bf(Wv[k * H_ + n]);
        } else {
            int e = g - 32768; int n = e >> 7, k = e & 127;
            W2T[e] = f2bf(W2[k * MID_ + n]);
        }
    } else {
        __shared__ float sq[32][132];
        __shared__ float sk[32][132];
        int bb = blockIdx.x - 144;
        int n0 = (bb >> 2) * 32, k0 = (bb & 3) * 32;
        for (int i = tid; i < 32 * 128; i += 256) {
            int r = i >> 7, c = i & 127;
            sq[r][c] = Wq[(k0 + r) * H_ + c];
            sk[r][c] = Wk[(n0 + r) * H_ + c];
        }
        __syncthreads();
        for (int i = tid; i < 1024; i += 256) {
            int kk = i & 31, nn = i >> 5;
            float a = 0.f;
            for (int j = 0; j < 128; ++j) a += sq[kk][j] * sk[nn][j];
            WqkT[(n0 + nn) * 128 + (k0 + kk)] = f2bf(a * RSQRT_H);
        }
    }
}

// ---------------------------------------------------------------------------
// 2-M-tile fused GEMM stage: C[m][n] = epi(A[abase+m][0:128] @ WT^T), m 0..31
// wave owns N-tiles {2w,2w+1}. EPI 0: none | 1: relu(+b)+pe (invalid rows->0)
// | 2: +b.  If HT: also write C transposed into hTp[n][row] (for nsum MFMA).
// ---------------------------------------------------------------------------
template <int EPI, bool HT>
__device__ __forceinline__ void mm2(const ushort* __restrict__ A, int abase,
                                    const ushort* __restrict__ WT,
                                    ushort* __restrict__ C,
                                    ushort* __restrict__ hTp,
                                    int wave, int lane,
                                    const float* __restrict__ bias,
                                    const float* __restrict__ pe, int srow0) {
    int l15 = lane & 15, quad = lane >> 4;
    short8 bfrag[2][4];
#pragma unroll
    for (int nt = 0; nt < 2; ++nt) {
        int n = (wave * 2 + nt) * 16 + l15;
#pragma unroll
        for (int ks = 0; ks < 4; ++ks)
            bfrag[nt][ks] = *(const short8*)(WT + n * 128 + ks * 32 + quad * 8);
    }
    float biasv[2] = {0.f, 0.f};
    if (EPI != 0) {
#pragma unroll
        for (int nt = 0; nt < 2; ++nt) biasv[nt] = bias[(wave * 2 + nt) * 16 + l15];
    }
#pragma unroll
    for (int mt = 0; mt < 2; ++mt) {
        short8 afrag[4];
#pragma unroll
        for (int ks = 0; ks < 4; ++ks)
            afrag[ks] = *(const short8*)(A + (abase + mt * 16 + l15) * LSTR + ks * 32 + quad * 8);
#pragma unroll
        for (int nt = 0; nt < 2; ++nt) {
            float4v acc = {0.f, 0.f, 0.f, 0.f};
#pragma unroll
            for (int ks = 0; ks < 4; ++ks)
                acc = __builtin_amdgcn_mfma_f32_16x16x32_bf16(afrag[ks], bfrag[nt][ks], acc, 0, 0, 0);
            int n = (wave * 2 + nt) * 16 + l15;
#pragma unroll
            for (int i = 0; i < 4; ++i) {
                int row = mt * 16 + quad * 4 + i;
                float v = acc[i];
                if (EPI == 1) {
                    int srow = srow0 + row;
                    v = (srow >= 0 && srow < S_)
                            ? (fmaxf(v + biasv[nt], 0.f) + pe[srow * H_ + n]) : 0.f;
                } else if (EPI == 2) v = v + biasv[nt];
                ushort bf = f2bf(v);
                C[row * LSTR + n] = bf;
                if (HT) hTp[n * HTS + row] = bf;
            }
        }
    }
}

// ---------------------------------------------------------------------------
// Fused kernel: 4096 blocks; block = (sequence b, tile t: 25 rows + halo 2).
// Pipeline: x->klds | S1 h=relu(x@W1+b1)+pe -> hlds + hT | S2 kq=h@Wqk'->klds
// | S3a scores=kq@h^T (MFMA, band in 3 tiles) -> slds; wave3 zeros wband
// | S3b softmax (25 thr) -> warr + wband | S3c nsum=wband@h (MFMA, via hT)
// -> klds | S4 ctx=nsum@Wv+bv -> hlds | S5 mid=relu(ctx@W2+b2)->klds, w->out
// | S6 out=mid@W3+b3.
// ---------------------------------------------------------------------------
__global__ __launch_bounds__(256, 4) void fused_kernel(
    const float* __restrict__ x, const ushort* __restrict__ W1T,
    const ushort* __restrict__ WqkT, const ushort* __restrict__ WvT,
    const ushort* __restrict__ W2T,
    const float* __restrict__ b1, const float* __restrict__ bv,
    const float* __restrict__ b2, const float* __restrict__ W3,
    const float* __restrict__ b3, const float* __restrict__ pe,
    float* __restrict__ out, float* __restrict__ wout) {
    __shared__ __attribute__((aligned(16))) ushort klds[KR * LSTR];
    __shared__ __attribute__((aligned(16))) ushort hlds[HR * LSTR];
    __shared__ __attribute__((aligned(16))) ushort hT[H_ * HTS];
    __shared__ __attribute__((aligned(16))) float  slds[KR * SSTR];
    __shared__ __attribute__((aligned(16))) ushort wband[KR * WSTR];
    __shared__ float warr[TILE * 5];

    int tid = threadIdx.x, wave = tid >> 6, lane = tid & 63;
    int l15 = lane & 15, quad = lane >> 4;
    int b = blockIdx.x >> 2, t = blockIdx.x & 3;
    int r0 = t * TILE;
    int srow0 = r0 - 2;  // seq row of local row 0

    // --- zero pad regions
    for (int i = tid; i < 29 * 18; i += 256) {          // klds rows 0..28, cols 100..135
        int r = i / 18, c = 100 + 2 * (i - r * 18);
        *(uint*)(klds + r * LSTR + c) = 0u;
    }
    for (int i = tid; i < 3 * 68; i += 256) {           // klds rows 29..31 full
        int r = 29 + i / 68, c = 2 * (i % 68);
        *(uint*)(klds + r * LSTR + c) = 0u;
    }
    for (int i = tid; i < 4 * 68; i += 256) {           // hlds rows 32..35 full
        int r = 32 + i / 68, c = 2 * (i % 68);
        *(uint*)(hlds + r * LSTR + c) = 0u;
    }
    // --- stage x tile as bf16 (rows max(r0-2,0)..min(r0+27,100))
    {
        int g0 = srow0 < 0 ? 0 : srow0;
        int g1 = (r0 + 27 < S_) ? (r0 + 27) : S_;
        int lr0 = g0 - srow0;
        const float* xb = x + ((size_t)b * S_ + g0) * IN_;
        int pairs = (g1 - g0) * 50;
        for (int p = tid; p < pairs; p += 256) {
            int row = p / 50;
            int c2 = (p - row * 50) * 2;
            const float* src = xb + row * IN_ + c2;
            uint pk = ((uint)f2bf(src[1]) << 16) | (uint)f2bf(src[0]);
            *(uint*)(klds + (lr0 + row) * LSTR + c2) = pk;
        }
    }
    __syncthreads();
    // S1: h -> hlds rows 0..31 (+ transposed copy into hT)
    mm2<1, true>(klds, 0, W1T, hlds, hT, wave, lane, b1, pe, srow0);
    __syncthreads();
    // S2: kq (pre-scaled by 1/sqrt(H) via WqkT) -> klds rows 0..31
    mm2<0, false>(hlds, 2, WqkT, klds, nullptr, wave, lane, nullptr, nullptr, 0);
    __syncthreads();
    // S3a: scores[q][j] = kq[q] . h[j]  (3 MFMA tiles); wave3 zeros wband
    if (wave < 3) {
        int qt = (wave == 2) ? 1 : 0;
        int ht = (wave == 0) ? 0 : 1;
        short8 afrag[4], bfrag[4];
#pragma unroll
        for (int ks = 0; ks < 4; ++ks) {
            afrag[ks] = *(const short8*)(klds + (qt * 16 + l15) * LSTR + ks * 32 + quad * 8);
            bfrag[ks] = *(const short8*)(hlds + (ht * 16 + l15) * LSTR + ks * 32 + quad * 8);
        }
        float4v acc = {0.f, 0.f, 0.f, 0.f};
#pragma unroll
        for (int ks = 0; ks < 4; ++ks)
            acc = __builtin_amdgcn_mfma_f32_16x16x32_bf16(afrag[ks], bfrag[ks], acc, 0, 0, 0);
#pragma unroll
        for (int i = 0; i < 4; ++i)
            slds[(qt * 16 + quad * 4 + i) * SSTR + ht * 16 + l15] = acc[i];
    } else {
        uint* wz = (uint*)wband;
        for (int i = lane; i < (KR * WSTR) / 2; i += 64) wz[i] = 0u;
    }
    __syncthreads();
    // S3b: softmax over the 5-wide band (25 threads)
    if (tid < TILE) {
        int i = tid;
        float sc5[5];
#pragma unroll
        for (int d = 0; d < 5; ++d) sc5[d] = slds[i * SSTR + i + d];  // j = i+d <-> m = 4-d
        float mx = sc5[0];
#pragma unroll
        for (int d = 1; d < 5; ++d) mx = fmaxf(mx, sc5[d]);
        float e5[5], ss = 0.f;
#pragma unroll
        for (int d = 0; d < 5; ++d) { e5[d] = __expf(sc5[d] - mx); ss += e5[d]; }
        float inv = 1.f / ss;
#pragma unroll
        for (int d = 0; d < 5; ++d) {
            float w = e5[d] * inv;
            wband[i * WSTR + i + d] = f2bf(w);
            warr[i * 5 + (4 - d)] = w;
        }
    }
    __syncthreads();
    // S3c: nsum = wband @ h  (A=wband [q][j], B=hT [dim][j]) -> klds
    {
        short8 afr[2];
        afr[0] = *(const short8*)(wband + l15 * WSTR + quad * 8);
        afr[1] = *(const short8*)(wband + (16 + l15) * WSTR + quad * 8);
#pragma unroll
        for (int ntt = 0; ntt < 2; ++ntt) {
            int n = (wave * 2 + ntt) * 16 + l15;
            short8 bfr = *(const short8*)(hT + n * HTS + quad * 8);
#pragma unroll
            for (int mt = 0; mt < 2; ++mt) {
                float4v acc = {0.f, 0.f, 0.f, 0.f};
                acc = __builtin_amdgcn_mfma_f32_16x16x32_bf16(afr[mt], bfr, acc, 0, 0, 0);
#pragma unroll
                for (int i = 0; i < 4; ++i)
                    klds[(mt * 16 + quad * 4 + i) * LSTR + n] = f2bf(acc[i]);
            }
        }
    }
    __syncthreads();
    // S4: ctx = nsum @ Wv + bv -> hlds rows 0..31
    mm2<2, false>(klds, 0, WvT, hlds, nullptr, wave, lane, bv, nullptr, 0);
    __syncthreads();
    // S5: mid = relu(ctx@W2+b2) -> klds cols 0..31; also flush w -> global
    if (tid < TILE * 5)
        wout[(size_t)b * (S_ * 5) + r0 * 5 + tid] = warr[tid];
    {
        int mt = wave & 1, nt = wave >> 1;
        short8 bfrag[4];
#pragma unroll
        for (int ks = 0; ks < 4; ++ks)
            bfrag[ks] = *(const short8*)(W2T + (nt * 16 + l15) * 128 + ks * 32 + quad * 8);
        float bias2 = b2[nt * 16 + l15];
        short8 afrag[4];
#pragma unroll
        for (int ks = 0; ks < 4; ++ks)
            afrag[ks] = *(const short8*)(hlds + (mt * 16 + l15) * LSTR + ks * 32 + quad * 8);
        float4v acc = {0.f, 0.f, 0.f, 0.f};
#pragma unroll
        for (int ks = 0; ks < 4; ++ks)
            acc = __builtin_amdgcn_mfma_f32_16x16x32_bf16(afrag[ks], bfrag[ks], acc, 0, 0, 0);
#pragma unroll
        for (int i = 0; i < 4; ++i) {
            int row = mt * 16 + quad * 4 + i;
            klds[row * LSTR + nt * 16 + l15] = f2bf(fmaxf(acc[i] + bias2, 0.f));
        }
    }
    __syncthreads();
    // S6: out = mid @ W3 + b3  (50 threads: one output scalar each)
    if (tid < TILE * 2) {
        int r = tid >> 1, c = tid & 1;
        float o = b3[c];
        const ushort* mr = klds + r * LSTR;
#pragma unroll
        for (int cs = 0; cs < 4; ++cs) {
            short8 v = *(const short8*)(mr + cs * 8);
#pragma unroll
            for (int j = 0; j < 8; ++j) o += bf2f((ushort)v[j]) * W3[(cs * 8 + j) * 2 + c];
        }
        out[((size_t)b * S_ + r0 + r) * OUT_ + c] = o;
    }
}

// ---------------------------------------------------------------------------
extern "C" void kernel_launch(void* const* d_in, const int* in_sizes, int n_in,
                              void* d_out, int out_size, void* d_ws, size_t ws_size,
                              hipStream_t stream) {
    const float* x  = (const float*)d_in[0];
    const float* W1 = (const float*)d_in[1];
    const float* b1 = (const float*)d_in[2];
    const float* Wq = (const float*)d_in[3];
    const float* Wk = (const float*)d_in[4];
    const float* Wv = (const float*)d_in[5];
    const float* bv = (const float*)d_in[6];
    const float* W2 = (const float*)d_in[7];
    const float* b2 = (const float*)d_in[8];
    const float* W3 = (const float*)d_in[9];
    const float* b3 = (const float*)d_in[10];
    const float* pe = (const float*)d_in[11];

    float* out  = (float*)d_out;             // (B,S,2)
    float* wout = out + (size_t)P_ * OUT_;   // (B,S,1,5)

    ushort* W1T  = (ushort*)d_ws;            // [128][128] bf16
    ushort* WqkT = W1T + 16384;
    ushort* WvT  = WqkT + 16384;
    ushort* W2T  = WvT + 16384;              // [32][128]

    prep_kernel<<<160, 256, 0, stream>>>(W1, Wv, W2, Wq, Wk, W1T, WvT, W2T, WqkT);
    fused_kernel<<<B_ * 4, 256, 0, stream>>>(x, W1T, WqkT, WvT, W2T,
                                             b1, bv, b2, W3, b3, pe, out, wout);
}

// Round 5
// 160.620 us; speedup vs baseline: 1.0472x; 1.0472x over previous
//
#include <hip/hip_runtime.h>
#include <hip/hip_bf16.h>

#define B_ 1024
#define S_ 100
#define IN_ 100
#define H_ 128
#define MID_ 32
#define OUT_ 2
#define P_ (B_ * S_)
#define RSQRT_H 0.08838834764831845f
#define LSTR 132     // klds/hlds row stride (bf16): 264 B, 8B-aligned rows
#define TILE 25      // center rows per block (4 tiles per sequence)
#define KR 32        // klds rows
#define HR 34        // hlds rows (S2 reads rows 2..33; 32..33 zeroed)
#define HTS 36       // hT row stride (bf16)
#define WSTR 36      // wband row stride (bf16)
#define SSC 20       // score scratch cols (fp32)

typedef __attribute__((ext_vector_type(8))) short short8;
typedef __attribute__((ext_vector_type(4))) float float4v;

__device__ __forceinline__ float bf2f(ushort u) {
    union { unsigned u; float f; } c; c.u = ((unsigned)u) << 16; return c.f;
}
__device__ __forceinline__ ushort f2bf(float x) {
    union { float f; unsigned u; } c; c.f = x;
    unsigned r = c.u + 0x7FFFu + ((c.u >> 16) & 1u);  // RNE
    return (ushort)(r >> 16);
}

// ---------------------------------------------------------------------------
// Prep (97 blocks):
//  0..63 : W1T[n][k] = W1[k][n] (k>=100 -> 0)                (bf16 [128][128])
//  64..79: WqkT[n][k] = RSQRT_H * sum_j Wq[k][j]*Wk[n][j]    (bf16 [128][128])
//  80..95: Wvw2T[n][k] = sum_j Wv[k][j]*W2[j][n]             (bf16 [32][128])
//  96    : bv2[n] = b2[n] + sum_j bv[j]*W2[j][n]             (fp32 [32])
// ---------------------------------------------------------------------------
__global__ __launch_bounds__(256) void prep_kernel(const float* __restrict__ W1,
                                                   const float* __restrict__ Wq,
                                                   const float* __restrict__ Wk,
                                                   const float* __restrict__ Wv,
                                                   const float* __restrict__ W2,
                                                   const float* __restrict__ bv,
                                                   const float* __restrict__ b2,
                                                   ushort* __restrict__ W1T,
                                                   ushort* __restrict__ WqkT,
                                                   ushort* __restrict__ Wvw2T,
                                                   float* __restrict__ bv2) {
    int tid = threadIdx.x;
    if (blockIdx.x < 64) {
        int g = blockIdx.x * 256 + tid;
        int n = g >> 7, k = g & 127;
        W1T[g] = (k < IN_) ? f2bf(W1[k * H_ + n]) : (ushort)0;
    } else if (blockIdx.x < 80) {
        __shared__ float sq[32][132];
        __shared__ float sk[32][132];
        int bb = blockIdx.x - 64;
        int n0 = (bb >> 2) * 32, k0 = (bb & 3) * 32;
        for (int i = tid; i < 32 * 128; i += 256) {
            int r = i >> 7, c = i & 127;
            sq[r][c] = Wq[(k0 + r) * H_ + c];
            sk[r][c] = Wk[(n0 + r) * H_ + c];
        }
        __syncthreads();
        for (int i = tid; i < 1024; i += 256) {
            int kk = i & 31, nn = i >> 5;
            float a = 0.f;
            for (int j = 0; j < 128; ++j) a += sq[kk][j] * sk[nn][j];
            WqkT[(n0 + nn) * 128 + (k0 + kk)] = f2bf(a * RSQRT_H);
        }
    } else if (blockIdx.x < 96) {
        int e = (blockIdx.x - 80) * 256 + tid;  // 0..4095
        int n = e >> 7, k = e & 127;
        float a = 0.f;
        for (int j = 0; j < 128; ++j) a += Wv[k * H_ + j] * W2[j * MID_ + n];
        Wvw2T[e] = f2bf(a);
    } else {
        if (tid < MID_) {
            float a = b2[tid];
            for (int j = 0; j < 128; ++j) a += bv[j] * W2[j * MID_ + tid];
            bv2[tid] = a;
        }
    }
}

// ---------------------------------------------------------------------------
// 2-M-tile GEMM stage (N=128): C[m][n] = epi(A[abase+m][0:128] @ WT^T)
// EPI 1: relu(+b)+pe with invalid-seq-row -> 0, plus transposed copy into hT
// EPI 0: plain.
// ---------------------------------------------------------------------------
template <int EPI, bool HT>
__device__ __forceinline__ void mm2(const ushort* __restrict__ A, int abase,
                                    const ushort* __restrict__ WT,
                                    ushort* __restrict__ C,
                                    ushort* __restrict__ hTp,
                                    int wave, int lane,
                                    const float* __restrict__ bias,
                                    const float* __restrict__ pe, int srow0) {
    int l15 = lane & 15, quad = lane >> 4;
    short8 bfrag[2][4];
#pragma unroll
    for (int nt = 0; nt < 2; ++nt) {
        int n = (wave * 2 + nt) * 16 + l15;
#pragma unroll
        for (int ks = 0; ks < 4; ++ks)
            bfrag[nt][ks] = *(const short8*)(WT + n * 128 + ks * 32 + quad * 8);
    }
    float biasv[2] = {0.f, 0.f};
    if (EPI == 1) {
#pragma unroll
        for (int nt = 0; nt < 2; ++nt) biasv[nt] = bias[(wave * 2 + nt) * 16 + l15];
    }
#pragma unroll
    for (int mt = 0; mt < 2; ++mt) {
        short8 afrag[4];
#pragma unroll
        for (int ks = 0; ks < 4; ++ks)
            afrag[ks] = *(const short8*)(A + (abase + mt * 16 + l15) * LSTR + ks * 32 + quad * 8);
#pragma unroll
        for (int nt = 0; nt < 2; ++nt) {
            float4v acc = {0.f, 0.f, 0.f, 0.f};
#pragma unroll
            for (int ks = 0; ks < 4; ++ks)
                acc = __builtin_amdgcn_mfma_f32_16x16x32_bf16(afrag[ks], bfrag[nt][ks], acc, 0, 0, 0);
            int n = (wave * 2 + nt) * 16 + l15;
            ushort bfv[4];
#pragma unroll
            for (int i = 0; i < 4; ++i) {
                int row = mt * 16 + quad * 4 + i;
                float v = acc[i];
                if (EPI == 1) {
                    int srow = srow0 + row;
                    v = (srow >= 0 && srow < S_)
                            ? (fmaxf(v + biasv[nt], 0.f) + pe[srow * H_ + n]) : 0.f;
                }
                bfv[i] = f2bf(v);
                C[row * LSTR + n] = bfv[i];
            }
            if (HT) {
                uint2 pk;
                pk.x = (uint)bfv[0] | ((uint)bfv[1] << 16);
                pk.y = (uint)bfv[2] | ((uint)bfv[3] << 16);
                *(uint2*)(hTp + n * HTS + mt * 16 + quad * 4) = pk;
            }
        }
    }
}

// ---------------------------------------------------------------------------
// Fused kernel: 4096 blocks; block = (seq b, tile t: 25 center rows, halo 2).
// x->klds | S1 h -> hlds+hT | S2 kq -> klds | S3 in-wave attn (waves 0,1):
// scores->softmax->w(global)+wband->nsum->klds | S5 mid=relu(nsum@Wvw2+bv2)
// -> hlds | S6 out. 5 barriers.
// ---------------------------------------------------------------------------
__global__ __launch_bounds__(256, 4) void fused_kernel(
    const float* __restrict__ x, const ushort* __restrict__ W1T,
    const ushort* __restrict__ WqkT, const ushort* __restrict__ Wvw2T,
    const float* __restrict__ bv2,
    const float* __restrict__ b1, const float* __restrict__ W3,
    const float* __restrict__ b3, const float* __restrict__ pe,
    float* __restrict__ out, float* __restrict__ wout) {
    __shared__ __attribute__((aligned(16))) ushort klds[KR * LSTR];   // x->kq->nsum
    __shared__ __attribute__((aligned(16))) ushort hlds[HR * LSTR];   // h -> mid
    __shared__ __attribute__((aligned(16))) ushort hT[H_ * HTS];      // h transposed
    __shared__ __attribute__((aligned(16))) ushort wband[KR * WSTR];  // softmax band
    __shared__ __attribute__((aligned(16))) float  sscr[2][16][SSC];  // score scratch

    int tid = threadIdx.x, wave = tid >> 6, lane = tid & 63;
    int l15 = lane & 15, quad = lane >> 4;
    int b = blockIdx.x >> 2, t = blockIdx.x & 3;
    int r0 = t * TILE;
    int srow0 = r0 - 2;  // seq row of local row 0

    // --- zero: klds K-pad cols (rows 0..28), klds rows 29..31, hlds rows
    //     32..33, wband (all). Total ~1312 uints.
    for (int i = tid; i < 29 * 14; i += 256) {       // klds rows 0..28 cols 100..127
        int r = i / 14, c = 100 + 2 * (i - r * 14);
        *(uint*)(klds + r * LSTR + c) = 0u;
    }
    for (int i = tid; i < 3 * 66; i += 256) {        // klds rows 29..31
        int r = 29 + i / 66, c = 2 * (i % 66);
        *(uint*)(klds + r * LSTR + c) = 0u;
    }
    for (int i = tid; i < 2 * 66; i += 256) {        // hlds rows 32..33
        int r = 32 + i / 66, c = 2 * (i % 66);
        *(uint*)(hlds + r * LSTR + c) = 0u;
    }
    for (int i = tid; i < (KR * WSTR) / 2; i += 256) // wband
        ((uint*)wband)[i] = 0u;

    // --- stage x tile, batched float4 loads then convert+store
    {
        int g0 = srow0 < 0 ? 0 : srow0;
        int g1 = (r0 + 27 < S_) ? (r0 + 27) : S_;
        int lr0 = g0 - srow0;
        const float* xb = x + ((size_t)b * S_ + g0) * IN_;
        int quads = (g1 - g0) * 25;
        float4 v[3];
#pragma unroll
        for (int it = 0; it < 3; ++it) {
            int p = tid + it * 256;
            if (p < quads) v[it] = *(const float4*)(xb + (p / 25) * IN_ + (p % 25) * 4);
        }
#pragma unroll
        for (int it = 0; it < 3; ++it) {
            int p = tid + it * 256;
            if (p < quads) {
                int row = p / 25, qr = p - row * 25;
                uint2 pk;
                pk.x = (uint)f2bf(v[it].x) | ((uint)f2bf(v[it].y) << 16);
                pk.y = (uint)f2bf(v[it].z) | ((uint)f2bf(v[it].w) << 16);
                *(uint2*)(klds + (lr0 + row) * LSTR + qr * 4) = pk;
            }
        }
    }
    __syncthreads();
    // S1: h = relu(x@W1+b1)+pe -> hlds rows 0..31 (+ hT transposed)
    mm2<1, true>(klds, 0, W1T, hlds, hT, wave, lane, b1, pe, srow0);
    __syncthreads();
    // S2: kq[q] = h[q+2] @ Wqk' -> klds rows 0..31 (pre-scaled by 1/sqrt(H))
    mm2<0, false>(hlds, 2, WqkT, klds, nullptr, wave, lane, nullptr, nullptr, 0);
    __syncthreads();
    // S3: in-wave attention. wave w in {0,1} owns q-tile qt=w.
    if (wave < 2) {
        int qt = wave;
        // scores: sc[q][j] = kq[q] . h[j], band j-q in [0,4]
        short8 afrag[4];
#pragma unroll
        for (int ks = 0; ks < 4; ++ks)
            afrag[ks] = *(const short8*)(klds + (qt * 16 + l15) * LSTR + ks * 32 + quad * 8);
#pragma unroll
        for (int ht = 0; ht < 2; ++ht) {
            if (ht < qt) continue;  // wave1 needs only ht=1
            short8 bfrag[4];
#pragma unroll
            for (int ks = 0; ks < 4; ++ks)
                bfrag[ks] = *(const short8*)(hlds + (ht * 16 + l15) * LSTR + ks * 32 + quad * 8);
            float4v acc = {0.f, 0.f, 0.f, 0.f};
#pragma unroll
            for (int ks = 0; ks < 4; ++ks)
                acc = __builtin_amdgcn_mfma_f32_16x16x32_bf16(afrag[ks], bfrag[ks], acc, 0, 0, 0);
            int c = (ht - qt) * 16 + l15;
            if (c < SSC) {
#pragma unroll
                for (int i = 0; i < 4; ++i) sscr[qt][quad * 4 + i][c] = acc[i];
            }
        }
        // softmax (valid q rows only); write w to global + band to wband
        int nq = (qt == 0) ? 16 : 9;
        if (lane < nq) {
            int q = qt * 16 + lane;
            float sc5[5];
#pragma unroll
            for (int d = 0; d < 5; ++d) sc5[d] = sscr[qt][lane][lane + d];
            float mx = sc5[0];
#pragma unroll
            for (int d = 1; d < 5; ++d) mx = fmaxf(mx, sc5[d]);
            float e5[5], ss = 0.f;
#pragma unroll
            for (int d = 0; d < 5; ++d) { e5[d] = __expf(sc5[d] - mx); ss += e5[d]; }
            float inv = 1.f / ss;
            float* wp = wout + ((size_t)b * S_ + r0 + q) * 5;
#pragma unroll
            for (int d = 0; d < 5; ++d) {
                float w = e5[d] * inv;
                wband[q * WSTR + q + d] = f2bf(w);
                wp[4 - d] = w;  // neighbor index m = 4 - d
            }
        }
        // nsum[q] = sum_j wband[q][j] * h[j]  (K window j in 0..31 covers band)
        short8 wfrag = *(const short8*)(wband + (qt * 16 + l15) * WSTR + quad * 8);
#pragma unroll
        for (int nt2 = 0; nt2 < 8; ++nt2) {
            short8 bfr = *(const short8*)(hT + (nt2 * 16 + l15) * HTS + quad * 8);
            float4v acc = {0.f, 0.f, 0.f, 0.f};
            acc = __builtin_amdgcn_mfma_f32_16x16x32_bf16(wfrag, bfr, acc, 0, 0, 0);
#pragma unroll
            for (int i = 0; i < 4; ++i)
                klds[(qt * 16 + quad * 4 + i) * LSTR + nt2 * 16 + l15] = f2bf(acc[i]);
        }
    }
    __syncthreads();
    // S5: mid = relu(nsum @ Wvw2 + bv2) -> hlds rows 0..31 cols 0..31
    {
        int mt = wave & 1, nt = wave >> 1;
        short8 bfrag[4];
#pragma unroll
        for (int ks = 0; ks < 4; ++ks)
            bfrag[ks] = *(const short8*)(Wvw2T + (nt * 16 + l15) * 128 + ks * 32 + quad * 8);
        float bias2 = bv2[nt * 16 + l15];
        short8 afrag[4];
#pragma unroll
        for (int ks = 0; ks < 4; ++ks)
            afrag[ks] = *(const short8*)(klds + (mt * 16 + l15) * LSTR + ks * 32 + quad * 8);
        float4v acc = {0.f, 0.f, 0.f, 0.f};
#pragma unroll
        for (int ks = 0; ks < 4; ++ks)
            acc = __builtin_amdgcn_mfma_f32_16x16x32_bf16(afrag[ks], bfrag[ks], acc, 0, 0, 0);
#pragma unroll
        for (int i = 0; i < 4; ++i) {
            int row = mt * 16 + quad * 4 + i;
            hlds[row * LSTR + nt * 16 + l15] = f2bf(fmaxf(acc[i] + bias2, 0.f));
        }
    }
    __syncthreads();
    // S6: out = mid @ W3 + b3  (50 threads, one output scalar each)
    if (tid < TILE * 2) {
        int r = tid >> 1, cc = tid & 1;
        float o = b3[cc];
        const ushort* mr = hlds + r * LSTR;
#pragma unroll
        for (int cs = 0; cs < 4; ++cs) {
            short8 v = *(const short8*)(mr + cs * 8);
#pragma unroll
            for (int j = 0; j < 8; ++j) o += bf2f((ushort)v[j]) * W3[(cs * 8 + j) * 2 + cc];
        }
        out[((size_t)b * S_ + r0 + r) * OUT_ + cc] = o;
    }
}

// ---------------------------------------------------------------------------
extern "C" void kernel_launch(void* const* d_in, const int* in_sizes, int n_in,
                              void* d_out, int out_size, void* d_ws, size_t ws_size,
                              hipStream_t stream) {
    const float* x  = (const float*)d_in[0];
    const float* W1 = (const float*)d_in[1];
    const float* b1 = (const float*)d_in[2];
    const float* Wq = (const float*)d_in[3];
    const float* Wk = (const float*)d_in[4];
    const float* Wv = (const float*)d_in[5];
    const float* bv = (const float*)d_in[6];
    const float* W2 = (const float*)d_in[7];
    const float* b2 = (const float*)d_in[8];
    const float* W3 = (const float*)d_in[9];
    const float* b3 = (const float*)d_in[10];
    const float* pe = (const float*)d_in[11];

    float* out  = (float*)d_out;             // (B,S,2)
    float* wout = out + (size_t)P_ * OUT_;   // (B,S,1,5)

    ushort* W1T   = (ushort*)d_ws;           // [128][128] bf16
    ushort* WqkT  = W1T + 16384;             // [128][128] bf16
    ushort* Wvw2T = WqkT + 16384;            // [32][128]  bf16
    float*  bv2   = (float*)(Wvw2T + 4096);  // [32] fp32

    prep_kernel<<<97, 256, 0, stream>>>(W1, Wq, Wk, Wv, W2, bv, b2,
                                        W1T, WqkT, Wvw2T, bv2);
    fused_kernel<<<B_ * 4, 256, 0, stream>>>(x, W1T, WqkT, Wvw2T, bv2,
                                             b1, W3, b3, pe, out, wout);
}